// Round 3
// baseline (593.901 us; speedup 1.0000x reference)
//
#include <hip/hip_runtime.h>
#include <hip/hip_cooperative_groups.h>

namespace cg = cooperative_groups;

#define NBATCH 16
#define NCH 64
#define CPG 4
#define NGRP 16
#define EPSV 1e-5f

typedef float f32x4 __attribute__((ext_vector_type(4)));

// ws layout (bytes):
//   0     : S1  [16][64] float  (4096)
//   4096  : S2  [16][64] float  (4096)
//   8192  : cnt [16] int        (64)   -- zeroed region ends at 8256

// ---------------------------------------------------------------------------
// Single cooperative kernel:
//   phase 1: per-block slice stats -> LDS -> global atomics  (reads data once)
//   grid.sync()
//   params : each block builds the 16x16 (batch,group) A/B table in LDS
//   phase 2: apply over the SAME slice this block read in phase 1.
// Rationale: data (256 MB) == L3 size; after phase 1 it is L3-resident, so
// phase 2's re-read comes from Infinity Cache instead of HBM (the R2
// reversed-sweep experiment confirmed the L3-reuse mechanism, +10 us from
// tail-only reuse across a launch boundary; fusing captures the whole range).
// Non-temporal out stores keep the write stream from evicting data lines.
// __launch_bounds__(256,4): cap 128 VGPR -> 4 blocks/CU co-residency
// guaranteed for the 1024-block cooperative grid (LDS 16.2 KB/block, ok).
// ---------------------------------------------------------------------------
__global__ __launch_bounds__(256, 4)
void ogn_fused(const float* __restrict__ data,
               const int* __restrict__ bid,
               float* __restrict__ S1,
               float* __restrict__ S2,
               int* __restrict__ cnt,
               const float* __restrict__ w,
               const float* __restrict__ bias,
               float* __restrict__ out,
               int N, int rows_per_block) {
    __shared__ float ls1[NBATCH * NCH];
    __shared__ float ls2[NBATCH * NCH];
    __shared__ int   lcnt[NBATCH];
    __shared__ float4 lA[NBATCH * NGRP];
    __shared__ float4 lB[NBATCH * NGRP];

    for (int i = threadIdx.x; i < NBATCH * NCH; i += blockDim.x) {
        ls1[i] = 0.f;
        ls2[i] = 0.f;
    }
    if (threadIdx.x < NBATCH) lcnt[threadIdx.x] = 0;
    __syncthreads();

    const int t     = threadIdx.x;
    const int c4    = t & 15;   // which float4 (== group, CPG=4) of the 64-ch row
    const int rlane = t >> 4;   // 0..15: row within a 16-row sweep

    long long row_begin = (long long)blockIdx.x * rows_per_block;
    long long row_end   = row_begin + rows_per_block;
    if (row_begin > N) row_begin = N;
    if (row_end > N) row_end = N;

    const float4* data4 = (const float4*)data;

    // ---------------- phase 1: slice stats ----------------
    {
        float4 s1 = make_float4(0.f, 0.f, 0.f, 0.f);
        float4 s2 = make_float4(0.f, 0.f, 0.f, 0.f);
        int cur = -1;
        int c   = 0;

#define FLUSH() do { if (cur >= 0) {                                   \
        int base_ = cur * NCH + c4 * 4;                                \
        atomicAdd(&ls1[base_ + 0], s1.x);                              \
        atomicAdd(&ls1[base_ + 1], s1.y);                              \
        atomicAdd(&ls1[base_ + 2], s1.z);                              \
        atomicAdd(&ls1[base_ + 3], s1.w);                              \
        atomicAdd(&ls2[base_ + 0], s2.x);                              \
        atomicAdd(&ls2[base_ + 1], s2.y);                              \
        atomicAdd(&ls2[base_ + 2], s2.z);                              \
        atomicAdd(&ls2[base_ + 3], s2.w);                              \
        if (c4 == 0) atomicAdd(&lcnt[cur], c);                         \
    } } while (0)

#define ACCV(vv) do {                                                  \
        s1.x += (vv).x; s1.y += (vv).y; s1.z += (vv).z; s1.w += (vv).w;\
        s2.x = fmaf((vv).x, (vv).x, s2.x);                             \
        s2.y = fmaf((vv).y, (vv).y, s2.y);                             \
        s2.z = fmaf((vv).z, (vv).z, s2.z);                             \
        s2.w = fmaf((vv).w, (vv).w, s2.w);                             \
    } while (0)

#define ACC1(bb, vv) do {                                              \
        if ((bb) != cur) {                                             \
            FLUSH();                                                   \
            s1 = make_float4(0.f, 0.f, 0.f, 0.f);                      \
            s2 = make_float4(0.f, 0.f, 0.f, 0.f);                      \
            c = 0; cur = (bb);                                         \
        }                                                              \
        ACCV(vv); c++;                                                 \
    } while (0)

        long long r = row_begin + rlane;

        for (; r + 48 < row_end; r += 64) {
            int b0 = bid[r];
            int b1 = bid[r + 16];
            int b2 = bid[r + 32];
            int b3 = bid[r + 48];
            float4 v0 = data4[r * 16 + c4];
            float4 v1 = data4[(r + 16) * 16 + c4];
            float4 v2 = data4[(r + 32) * 16 + c4];
            float4 v3 = data4[(r + 48) * 16 + c4];
            if (((b0 == cur) & (b1 == cur) & (b2 == cur) & (b3 == cur)) != 0) {
                ACCV(v0); ACCV(v1); ACCV(v2); ACCV(v3);
                c += 4;
            } else {
                ACC1(b0, v0);
                ACC1(b1, v1);
                ACC1(b2, v2);
                ACC1(b3, v3);
            }
        }
        for (; r < row_end; r += 16) {
            int b = bid[r];
            float4 v = data4[r * 16 + c4];
            ACC1(b, v);
        }
        FLUSH();
        __syncthreads();

#undef ACC1
#undef ACCV
#undef FLUSH

        for (int i = threadIdx.x; i < NBATCH * NCH; i += blockDim.x) {
            float v1 = ls1[i];
            float v2 = ls2[i];
            if (v1 != 0.f) atomicAdd(&S1[i], v1);
            if (v2 != 0.f) atomicAdd(&S2[i], v2);
        }
        if (threadIdx.x < NBATCH) {
            int v = lcnt[threadIdx.x];
            if (v != 0) atomicAdd(&cnt[threadIdx.x], v);
        }
    }

    // ---------------- grid-wide barrier ----------------
    cg::this_grid().sync();

    // ---------------- params: A/B table into LDS ----------------
    // Agent-scope atomic loads: bypass possibly-stale per-XCD cached copies.
    if (t < NBATCH * NGRP) {
        int b = t >> 4;        // batch
        int g = t & 15;        // group == float4 chunk (CPG == 4)
        int base = b * NCH + g * CPG;
        float s1g = 0.f, s2g = 0.f;
#pragma unroll
        for (int k = 0; k < CPG; ++k) {
            s1g += __hip_atomic_load(&S1[base + k], __ATOMIC_RELAXED, __HIP_MEMORY_SCOPE_AGENT);
            s2g += __hip_atomic_load(&S2[base + k], __ATOMIC_RELAXED, __HIP_MEMORY_SCOPE_AGENT);
        }
        int   cntb      = __hip_atomic_load(&cnt[b], __ATOMIC_RELAXED, __HIP_MEMORY_SCOPE_AGENT);
        float countf    = (float)cntb * (float)CPG;
        float inv_count = 1.f / (countf + EPSV);
        float mean      = s1g * inv_count;
        float var       = inv_count * (s2g - 2.f * mean * s1g + countf * mean * mean);
        float inv_std   = rsqrtf(var + EPSV);

        float4 wv = ((const float4*)w)[g];
        float4 bv = ((const float4*)bias)[g];
        float4 a4, b4;
        a4.x = inv_std * wv.x; b4.x = bv.x - mean * a4.x;
        a4.y = inv_std * wv.y; b4.y = bv.y - mean * a4.y;
        a4.z = inv_std * wv.z; b4.z = bv.z - mean * a4.z;
        a4.w = inv_std * wv.w; b4.w = bv.w - mean * a4.w;
        lA[b * NGRP + g] = a4;
        lB[b * NGRP + g] = b4;
    }
    __syncthreads();

    // ---------------- phase 2: apply over own (L3-hot) slice ----------------
    {
        float4* o4 = (float4*)out;
        for (long long r = row_begin + rlane; r < row_end; r += 16) {
            int b = bid[r];
            float4 v  = data4[r * 16 + c4];
            float4 a  = lA[b * NGRP + c4];
            float4 bb = lB[b * NGRP + c4];
            f32x4 res;
            res.x = fmaf(v.x, a.x, bb.x);
            res.y = fmaf(v.y, a.y, bb.y);
            res.z = fmaf(v.z, a.z, bb.z);
            res.w = fmaf(v.w, a.w, bb.w);
            __builtin_nontemporal_store(res, (f32x4*)&o4[r * 16 + c4]);
        }
    }
}

extern "C" void kernel_launch(void* const* d_in, const int* in_sizes, int n_in,
                              void* d_out, int out_size, void* d_ws, size_t ws_size,
                              hipStream_t stream) {
    const float* data = (const float*)d_in[0];
    const int*   bid  = (const int*)d_in[1];
    const float* w    = (const float*)d_in[2];
    const float* bias = (const float*)d_in[3];
    float* out = (float*)d_out;

    int N = in_sizes[1];  // batch_id count

    char* ws = (char*)d_ws;
    float* S1  = (float*)(ws + 0);
    float* S2  = (float*)(ws + 4096);
    int*   cnt = (int*)  (ws + 8192);

    // zero the accumulator region (S1, S2, cnt)
    hipMemsetAsync(d_ws, 0, 8256, stream);

    const int GRID = 1024;  // 4 blocks/CU -> guaranteed co-residency w/ launch_bounds
    int rows_per_block = (N + GRID - 1) / GRID;

    void* args[] = {
        (void*)&data, (void*)&bid,
        (void*)&S1, (void*)&S2, (void*)&cnt,
        (void*)&w, (void*)&bias, (void*)&out,
        (void*)&N, (void*)&rows_per_block
    };
    hipLaunchCooperativeKernel((void*)ogn_fused, dim3(GRID), dim3(256),
                               args, 0, stream);
}

// Round 5
// 582.420 us; speedup vs baseline: 1.0197x; 1.0197x over previous
//
#include <hip/hip_runtime.h>
#include <hip/hip_cooperative_groups.h>

namespace cg = cooperative_groups;

#define NBATCH 16
#define NCH 64
#define CPG 4
#define NGRP 16
#define EPSV 1e-5f

typedef float f32x4 __attribute__((ext_vector_type(4)));

// ws layout (bytes):
//   0     : S1  [16][64] float  (4096)
//   4096  : S2  [16][64] float  (4096)
//   8192  : cnt [16] int        (64)   -- zeroed region ends at 8256

// ===========================================================================
// Fused cooperative kernel (R3 structure, verified FETCH=266MB single HBM
// pass).  R5: LDS overlaid (lA/lB reuse ls1/ls2 -> 8.3 KB/block) and grid
// sized by the runtime's own occupancy query so the coop launch cannot be
// rejected (R4 lesson: unchecked coop launch failed silently at 2048).
// ===========================================================================
__global__ __launch_bounds__(256, 8)
void ogn_fused(const float* __restrict__ data,
               const int* __restrict__ bid,
               float* __restrict__ S1,
               float* __restrict__ S2,
               int* __restrict__ cnt,
               const float* __restrict__ w,
               const float* __restrict__ bias,
               float* __restrict__ out,
               int N, int rows_per_block) {
    // Overlay: phase 1 uses lsA/lsB as float accumulators ls1/ls2;
    // after grid.sync() the same memory holds the A/B float4 table.
    __shared__ float4 lsA[NBATCH * NGRP];   // 4 KB
    __shared__ float4 lsB[NBATCH * NGRP];   // 4 KB
    __shared__ int    lcnt[NBATCH];

    float* ls1 = (float*)lsA;
    float* ls2 = (float*)lsB;

    for (int i = threadIdx.x; i < NBATCH * NCH; i += blockDim.x) {
        ls1[i] = 0.f;
        ls2[i] = 0.f;
    }
    if (threadIdx.x < NBATCH) lcnt[threadIdx.x] = 0;
    __syncthreads();

    const int t     = threadIdx.x;
    const int c4    = t & 15;   // which float4 (== group, CPG=4) of the 64-ch row
    const int rlane = t >> 4;   // 0..15: row within a 16-row sweep

    long long row_begin = (long long)blockIdx.x * rows_per_block;
    long long row_end   = row_begin + rows_per_block;
    if (row_begin > N) row_begin = N;
    if (row_end > N) row_end = N;

    const float4* data4 = (const float4*)data;

    // ---------------- phase 1: slice stats ----------------
    {
        float4 s1 = make_float4(0.f, 0.f, 0.f, 0.f);
        float4 s2 = make_float4(0.f, 0.f, 0.f, 0.f);
        int cur = -1;
        int c   = 0;

#define FLUSH() do { if (cur >= 0) {                                   \
        int base_ = cur * NCH + c4 * 4;                                \
        atomicAdd(&ls1[base_ + 0], s1.x);                              \
        atomicAdd(&ls1[base_ + 1], s1.y);                              \
        atomicAdd(&ls1[base_ + 2], s1.z);                              \
        atomicAdd(&ls1[base_ + 3], s1.w);                              \
        atomicAdd(&ls2[base_ + 0], s2.x);                              \
        atomicAdd(&ls2[base_ + 1], s2.y);                              \
        atomicAdd(&ls2[base_ + 2], s2.z);                              \
        atomicAdd(&ls2[base_ + 3], s2.w);                              \
        if (c4 == 0) atomicAdd(&lcnt[cur], c);                         \
    } } while (0)

#define ACCV(vv) do {                                                  \
        s1.x += (vv).x; s1.y += (vv).y; s1.z += (vv).z; s1.w += (vv).w;\
        s2.x = fmaf((vv).x, (vv).x, s2.x);                             \
        s2.y = fmaf((vv).y, (vv).y, s2.y);                             \
        s2.z = fmaf((vv).z, (vv).z, s2.z);                             \
        s2.w = fmaf((vv).w, (vv).w, s2.w);                             \
    } while (0)

#define ACC1(bb, vv) do {                                              \
        if ((bb) != cur) {                                             \
            FLUSH();                                                   \
            s1 = make_float4(0.f, 0.f, 0.f, 0.f);                      \
            s2 = make_float4(0.f, 0.f, 0.f, 0.f);                      \
            c = 0; cur = (bb);                                         \
        }                                                              \
        ACCV(vv); c++;                                                 \
    } while (0)

        long long r = row_begin + rlane;

        for (; r + 48 < row_end; r += 64) {
            int b0 = bid[r];
            int b1 = bid[r + 16];
            int b2 = bid[r + 32];
            int b3 = bid[r + 48];
            float4 v0 = data4[r * 16 + c4];
            float4 v1 = data4[(r + 16) * 16 + c4];
            float4 v2 = data4[(r + 32) * 16 + c4];
            float4 v3 = data4[(r + 48) * 16 + c4];
            if (((b0 == cur) & (b1 == cur) & (b2 == cur) & (b3 == cur)) != 0) {
                ACCV(v0); ACCV(v1); ACCV(v2); ACCV(v3);
                c += 4;
            } else {
                ACC1(b0, v0);
                ACC1(b1, v1);
                ACC1(b2, v2);
                ACC1(b3, v3);
            }
        }
        for (; r < row_end; r += 16) {
            int b = bid[r];
            float4 v = data4[r * 16 + c4];
            ACC1(b, v);
        }
        FLUSH();
        __syncthreads();

#undef ACC1
#undef ACCV
#undef FLUSH

        for (int i = threadIdx.x; i < NBATCH * NCH; i += blockDim.x) {
            float v1 = ls1[i];
            float v2 = ls2[i];
            if (v1 != 0.f) atomicAdd(&S1[i], v1);
            if (v2 != 0.f) atomicAdd(&S2[i], v2);
        }
        if (threadIdx.x < NBATCH) {
            int v = lcnt[threadIdx.x];
            if (v != 0) atomicAdd(&cnt[threadIdx.x], v);
        }
    }

    // ---------------- grid-wide barrier ----------------
    // (also separates the last ls1/ls2 reads from the lA/lB overlay writes)
    cg::this_grid().sync();

    // ---------------- params: A/B table into (overlaid) LDS ----------------
    if (t < NBATCH * NGRP) {
        int b = t >> 4;        // batch
        int g = t & 15;        // group == float4 chunk (CPG == 4)
        int base = b * NCH + g * CPG;
        float s1g = 0.f, s2g = 0.f;
#pragma unroll
        for (int k = 0; k < CPG; ++k) {
            s1g += __hip_atomic_load(&S1[base + k], __ATOMIC_RELAXED, __HIP_MEMORY_SCOPE_AGENT);
            s2g += __hip_atomic_load(&S2[base + k], __ATOMIC_RELAXED, __HIP_MEMORY_SCOPE_AGENT);
        }
        int   cntb      = __hip_atomic_load(&cnt[b], __ATOMIC_RELAXED, __HIP_MEMORY_SCOPE_AGENT);
        float countf    = (float)cntb * (float)CPG;
        float inv_count = 1.f / (countf + EPSV);
        float mean      = s1g * inv_count;
        float var       = inv_count * (s2g - 2.f * mean * s1g + countf * mean * mean);
        float inv_std   = rsqrtf(var + EPSV);

        float4 wv = ((const float4*)w)[g];
        float4 bv = ((const float4*)bias)[g];
        float4 a4, b4;
        a4.x = inv_std * wv.x; b4.x = bv.x - mean * a4.x;
        a4.y = inv_std * wv.y; b4.y = bv.y - mean * a4.y;
        a4.z = inv_std * wv.z; b4.z = bv.z - mean * a4.z;
        a4.w = inv_std * wv.w; b4.w = bv.w - mean * a4.w;
        lsA[b * NGRP + g] = a4;
        lsB[b * NGRP + g] = b4;
    }
    __syncthreads();

    // ---------------- phase 2: apply over own (L3-hot) slice ----------------
    {
        float4* o4 = (float4*)out;
        long long r = row_begin + rlane;
        for (; r + 48 < row_end; r += 64) {
            int b0 = bid[r];
            int b1 = bid[r + 16];
            int b2 = bid[r + 32];
            int b3 = bid[r + 48];
            float4 v0 = data4[r * 16 + c4];
            float4 v1 = data4[(r + 16) * 16 + c4];
            float4 v2 = data4[(r + 32) * 16 + c4];
            float4 v3 = data4[(r + 48) * 16 + c4];
#define APPLY1(rr, bb, vv) do {                                        \
            float4 a_  = lsA[(bb) * NGRP + c4];                        \
            float4 b_  = lsB[(bb) * NGRP + c4];                        \
            f32x4 res_;                                                \
            res_.x = fmaf((vv).x, a_.x, b_.x);                         \
            res_.y = fmaf((vv).y, a_.y, b_.y);                         \
            res_.z = fmaf((vv).z, a_.z, b_.z);                         \
            res_.w = fmaf((vv).w, a_.w, b_.w);                         \
            __builtin_nontemporal_store(res_, (f32x4*)&o4[(rr) * 16 + c4]); \
        } while (0)
            APPLY1(r, b0, v0);
            APPLY1(r + 16, b1, v1);
            APPLY1(r + 32, b2, v2);
            APPLY1(r + 48, b3, v3);
        }
        for (; r < row_end; r += 16) {
            int b = bid[r];
            float4 v = data4[r * 16 + c4];
            APPLY1(r, b, v);
        }
#undef APPLY1
    }
}

// ===========================================================================
// Fallback path (proven R2 structure, 502 us) — used only if the coop
// launch is not possible; never silently drop the output again.
// ===========================================================================
__global__ void ogn_stats_fb(const float* __restrict__ data,
                             const int* __restrict__ bid,
                             float* __restrict__ S1,
                             float* __restrict__ S2,
                             int* __restrict__ cnt,
                             int N, int rows_per_block) {
    __shared__ float ls1[NBATCH * NCH];
    __shared__ float ls2[NBATCH * NCH];
    __shared__ int   lcnt[NBATCH];

    for (int i = threadIdx.x; i < NBATCH * NCH; i += blockDim.x) {
        ls1[i] = 0.f;
        ls2[i] = 0.f;
    }
    if (threadIdx.x < NBATCH) lcnt[threadIdx.x] = 0;
    __syncthreads();

    const int t     = threadIdx.x;
    const int c4    = t & 15;
    const int rlane = t >> 4;

    long long row_begin = (long long)blockIdx.x * rows_per_block;
    long long row_end   = row_begin + rows_per_block;
    if (row_begin > N) row_begin = N;
    if (row_end > N) row_end = N;

    const float4* data4 = (const float4*)data;

    float4 s1 = make_float4(0.f, 0.f, 0.f, 0.f);
    float4 s2 = make_float4(0.f, 0.f, 0.f, 0.f);
    int cur = -1;
    int c   = 0;

    for (long long r = row_begin + rlane; r < row_end; r += 16) {
        int b = bid[r];
        if (b != cur) {
            if (cur >= 0) {
                int base = cur * NCH + c4 * 4;
                atomicAdd(&ls1[base + 0], s1.x);
                atomicAdd(&ls1[base + 1], s1.y);
                atomicAdd(&ls1[base + 2], s1.z);
                atomicAdd(&ls1[base + 3], s1.w);
                atomicAdd(&ls2[base + 0], s2.x);
                atomicAdd(&ls2[base + 1], s2.y);
                atomicAdd(&ls2[base + 2], s2.z);
                atomicAdd(&ls2[base + 3], s2.w);
                if (c4 == 0) atomicAdd(&lcnt[cur], c);
            }
            s1 = make_float4(0.f, 0.f, 0.f, 0.f);
            s2 = make_float4(0.f, 0.f, 0.f, 0.f);
            c = 0;
            cur = b;
        }
        float4 v = data4[r * 16 + c4];
        s1.x += v.x; s1.y += v.y; s1.z += v.z; s1.w += v.w;
        s2.x = fmaf(v.x, v.x, s2.x);
        s2.y = fmaf(v.y, v.y, s2.y);
        s2.z = fmaf(v.z, v.z, s2.z);
        s2.w = fmaf(v.w, v.w, s2.w);
        c++;
    }
    if (cur >= 0) {
        int base = cur * NCH + c4 * 4;
        atomicAdd(&ls1[base + 0], s1.x);
        atomicAdd(&ls1[base + 1], s1.y);
        atomicAdd(&ls1[base + 2], s1.z);
        atomicAdd(&ls1[base + 3], s1.w);
        atomicAdd(&ls2[base + 0], s2.x);
        atomicAdd(&ls2[base + 1], s2.y);
        atomicAdd(&ls2[base + 2], s2.z);
        atomicAdd(&ls2[base + 3], s2.w);
        if (c4 == 0) atomicAdd(&lcnt[cur], c);
    }
    __syncthreads();

    for (int i = threadIdx.x; i < NBATCH * NCH; i += blockDim.x) {
        float v1 = ls1[i];
        float v2 = ls2[i];
        if (v1 != 0.f) atomicAdd(&S1[i], v1);
        if (v2 != 0.f) atomicAdd(&S2[i], v2);
    }
    if (threadIdx.x < NBATCH) {
        int v = lcnt[threadIdx.x];
        if (v != 0) atomicAdd(&cnt[threadIdx.x], v);
    }
}

__global__ void ogn_apply_fb(const float* __restrict__ data,
                             const int* __restrict__ bid,
                             const float* __restrict__ S1,
                             const float* __restrict__ S2,
                             const int* __restrict__ cnt,
                             const float* __restrict__ w,
                             const float* __restrict__ bias,
                             float* __restrict__ out,
                             long long total4) {
    __shared__ float4 lA[NBATCH * NGRP];
    __shared__ float4 lB[NBATCH * NGRP];

    const int t = threadIdx.x;
    if (t < NBATCH * NGRP) {
        int b = t >> 4;
        int g = t & 15;
        int base = b * NCH + g * CPG;
        float s1g = 0.f, s2g = 0.f;
#pragma unroll
        for (int k = 0; k < CPG; ++k) {
            s1g += S1[base + k];
            s2g += S2[base + k];
        }
        float countf    = (float)cnt[b] * (float)CPG;
        float inv_count = 1.f / (countf + EPSV);
        float mean      = s1g * inv_count;
        float var       = inv_count * (s2g - 2.f * mean * s1g + countf * mean * mean);
        float inv_std   = rsqrtf(var + EPSV);

        float4 wv = ((const float4*)w)[g];
        float4 bv = ((const float4*)bias)[g];
        float4 a4, b4;
        a4.x = inv_std * wv.x; b4.x = bv.x - mean * a4.x;
        a4.y = inv_std * wv.y; b4.y = bv.y - mean * a4.y;
        a4.z = inv_std * wv.z; b4.z = bv.z - mean * a4.z;
        a4.w = inv_std * wv.w; b4.w = bv.w - mean * a4.w;
        lA[b * NGRP + g] = a4;
        lB[b * NGRP + g] = b4;
    }
    __syncthreads();

    const float4* d4 = (const float4*)data;
    float4* o4 = (float4*)out;

    long long i      = (long long)blockIdx.x * blockDim.x + threadIdx.x;
    long long stride = (long long)gridDim.x * blockDim.x;

    for (; i < total4; i += stride) {
        long long j   = total4 - 1 - i;
        long long row = j >> 4;
        int c4 = (int)(j & 15);
        int b  = bid[row];
        float4 v  = d4[j];
        float4 a  = lA[b * NGRP + c4];
        float4 bb = lB[b * NGRP + c4];
        f32x4 r;
        r.x = fmaf(v.x, a.x, bb.x);
        r.y = fmaf(v.y, a.y, bb.y);
        r.z = fmaf(v.z, a.z, bb.z);
        r.w = fmaf(v.w, a.w, bb.w);
        __builtin_nontemporal_store(r, (f32x4*)&o4[j]);
    }
}

extern "C" void kernel_launch(void* const* d_in, const int* in_sizes, int n_in,
                              void* d_out, int out_size, void* d_ws, size_t ws_size,
                              hipStream_t stream) {
    const float* data = (const float*)d_in[0];
    const int*   bid  = (const int*)d_in[1];
    const float* w    = (const float*)d_in[2];
    const float* bias = (const float*)d_in[3];
    float* out = (float*)d_out;

    int N = in_sizes[1];  // batch_id count

    char* ws = (char*)d_ws;
    float* S1  = (float*)(ws + 0);
    float* S2  = (float*)(ws + 4096);
    int*   cnt = (int*)  (ws + 8192);

    // zero the accumulator region (S1, S2, cnt)
    hipMemsetAsync(d_ws, 0, 8256, stream);

    // Grid sized by the runtime's own occupancy computation (cached).
    static int s_grid = -1;
    if (s_grid < 0) {
        int maxB = 0;
        hipError_t e1 = hipOccupancyMaxActiveBlocksPerMultiprocessor(
            &maxB, (const void*)ogn_fused, 256, 0);
        hipDeviceProp_t prop;
        hipError_t e2 = hipGetDeviceProperties(&prop, 0);
        if (e1 == hipSuccess && e2 == hipSuccess && maxB > 0)
            s_grid = maxB * prop.multiProcessorCount;
        else
            s_grid = 0;  // coop not usable -> fallback
    }

    bool done = false;
    if (s_grid >= 256) {
        int grid = s_grid;
        int rows_per_block = (int)((N + (long long)grid - 1) / grid);
        void* args[] = {
            (void*)&data, (void*)&bid,
            (void*)&S1, (void*)&S2, (void*)&cnt,
            (void*)&w, (void*)&bias, (void*)&out,
            (void*)&N, (void*)&rows_per_block
        };
        hipError_t e = hipLaunchCooperativeKernel((void*)ogn_fused, dim3(grid),
                                                  dim3(256), args, 0, stream);
        done = (e == hipSuccess);
    }

    if (!done) {
        // proven two-kernel path (R2)
        const int NB1 = 2048;
        int rows_per_block = (N + NB1 - 1) / NB1;
        ogn_stats_fb<<<NB1, 256, 0, stream>>>(data, bid, S1, S2, cnt, N, rows_per_block);
        long long total4 = (long long)N * (NCH / 4);
        ogn_apply_fb<<<4096, 256, 0, stream>>>(data, bid, S1, S2, cnt, w, bias, out, total4);
    }
}

// Round 6
// 505.185 us; speedup vs baseline: 1.1756x; 1.1529x over previous
//
#include <hip/hip_runtime.h>

#define NBATCH 16
#define NCH 64
#define CPG 4
#define NGRP 16
#define EPSV 1e-5f

typedef float f32x4 __attribute__((ext_vector_type(4)));

// ws layout (bytes):
//   0     : S1  [16][64] float  (4096)
//   4096  : S2  [16][64] float  (4096)
//   8192  : cnt [16] int        (64)   -- zeroed region ends at 8256
//
// R6 design (post R3/R5 evidence):
//  - two plain kernels; the launch boundary is the barrier (CP-pipelined,
//    measured far cheaper than cg::grid.sync which scaled ~+120us with
//    participant count).
//  - bid[] is SORTED with only 15 boundaries in 1M rows. With 2048
//    contiguous slices, >=2033 blocks are single-segment: read bid[first]
//    and bid[last]; if equal, the hot loop carries NO bid loads, NO
//    segment-switch branches (stats), and A/B hoisted to REGISTERS (apply)
//    -> both hot loops are pure streams like the 6.5 TB/s fill.
//  - stats at 2048 blocks is fully resident -> leaves all 256 MB of data
//    L3-resident (proven R3: FETCH=266MB for two passes); apply re-reads
//    mostly from L3; nt-stores keep the write stream from evicting it.

// ---------------------------------------------------------------------------
// Pass 1: per-segment sum / sumsq / count.
// ---------------------------------------------------------------------------
__global__ __launch_bounds__(256)
void ogn_stats(const float* __restrict__ data,
               const int* __restrict__ bid,
               float* __restrict__ S1,
               float* __restrict__ S2,
               int* __restrict__ cnt,
               int N, int rows_per_block) {
    __shared__ float ls1[NBATCH * NCH];
    __shared__ float ls2[NBATCH * NCH];
    __shared__ int   lcnt[NBATCH];

    for (int i = threadIdx.x; i < NBATCH * NCH; i += blockDim.x) {
        ls1[i] = 0.f;
        ls2[i] = 0.f;
    }
    if (threadIdx.x < NBATCH) lcnt[threadIdx.x] = 0;
    __syncthreads();

    const int t     = threadIdx.x;
    const int c4    = t & 15;   // float4 chunk (== group) of the 64-ch row
    const int rlane = t >> 4;   // 0..15: row within a 16-row sweep

    long long row_begin = (long long)blockIdx.x * rows_per_block;
    long long row_end   = row_begin + rows_per_block;
    if (row_begin > N) row_begin = N;
    if (row_end > N) row_end = N;

    const float4* data4 = (const float4*)data;

#define ACCV(vv) do {                                                  \
        s1.x += (vv).x; s1.y += (vv).y; s1.z += (vv).z; s1.w += (vv).w;\
        s2.x = fmaf((vv).x, (vv).x, s2.x);                             \
        s2.y = fmaf((vv).y, (vv).y, s2.y);                             \
        s2.z = fmaf((vv).z, (vv).z, s2.z);                             \
        s2.w = fmaf((vv).w, (vv).w, s2.w);                             \
    } while (0)

    if (row_begin < row_end) {
        const int b0 = bid[row_begin];
        const int b1 = bid[row_end - 1];

        if (b0 == b1) {
            // ---------- fast path: single segment, pure stream ----------
            float4 s1 = make_float4(0.f, 0.f, 0.f, 0.f);
            float4 s2 = make_float4(0.f, 0.f, 0.f, 0.f);
            long long r = row_begin + rlane;
            for (; r + 48 < row_end; r += 64) {
                float4 v0 = data4[r * 16 + c4];
                float4 v1 = data4[(r + 16) * 16 + c4];
                float4 v2 = data4[(r + 32) * 16 + c4];
                float4 v3 = data4[(r + 48) * 16 + c4];
                ACCV(v0); ACCV(v1); ACCV(v2); ACCV(v3);
            }
            for (; r < row_end; r += 16) {
                float4 v = data4[r * 16 + c4];
                ACCV(v);
            }
            int base = b0 * NCH + c4 * 4;
            atomicAdd(&ls1[base + 0], s1.x);
            atomicAdd(&ls1[base + 1], s1.y);
            atomicAdd(&ls1[base + 2], s1.z);
            atomicAdd(&ls1[base + 3], s1.w);
            atomicAdd(&ls2[base + 0], s2.x);
            atomicAdd(&ls2[base + 1], s2.y);
            atomicAdd(&ls2[base + 2], s2.z);
            atomicAdd(&ls2[base + 3], s2.w);
            if (t == 0) lcnt[b0] = (int)(row_end - row_begin);
        } else {
            // ---------- slow path (<=15 boundary-straddling blocks) ----------
            float4 s1 = make_float4(0.f, 0.f, 0.f, 0.f);
            float4 s2 = make_float4(0.f, 0.f, 0.f, 0.f);
            int cur = -1;
            int c   = 0;
            for (long long r = row_begin + rlane; r < row_end; r += 16) {
                int b = bid[r];
                if (b != cur) {
                    if (cur >= 0) {
                        int base = cur * NCH + c4 * 4;
                        atomicAdd(&ls1[base + 0], s1.x);
                        atomicAdd(&ls1[base + 1], s1.y);
                        atomicAdd(&ls1[base + 2], s1.z);
                        atomicAdd(&ls1[base + 3], s1.w);
                        atomicAdd(&ls2[base + 0], s2.x);
                        atomicAdd(&ls2[base + 1], s2.y);
                        atomicAdd(&ls2[base + 2], s2.z);
                        atomicAdd(&ls2[base + 3], s2.w);
                        if (c4 == 0) atomicAdd(&lcnt[cur], c);
                    }
                    s1 = make_float4(0.f, 0.f, 0.f, 0.f);
                    s2 = make_float4(0.f, 0.f, 0.f, 0.f);
                    c = 0;
                    cur = b;
                }
                float4 v = data4[r * 16 + c4];
                ACCV(v);
                c++;
            }
            if (cur >= 0) {
                int base = cur * NCH + c4 * 4;
                atomicAdd(&ls1[base + 0], s1.x);
                atomicAdd(&ls1[base + 1], s1.y);
                atomicAdd(&ls1[base + 2], s1.z);
                atomicAdd(&ls1[base + 3], s1.w);
                atomicAdd(&ls2[base + 0], s2.x);
                atomicAdd(&ls2[base + 1], s2.y);
                atomicAdd(&ls2[base + 2], s2.z);
                atomicAdd(&ls2[base + 3], s2.w);
                if (c4 == 0) atomicAdd(&lcnt[cur], c);
            }
        }
    }
#undef ACCV
    __syncthreads();

    for (int i = threadIdx.x; i < NBATCH * NCH; i += blockDim.x) {
        float v1 = ls1[i];
        float v2 = ls2[i];
        if (v1 != 0.f) atomicAdd(&S1[i], v1);
        if (v2 != 0.f) atomicAdd(&S2[i], v2);
    }
    if (threadIdx.x < NBATCH) {
        int v = lcnt[threadIdx.x];
        if (v != 0) atomicAdd(&cnt[threadIdx.x], v);
    }
}

// ---------------------------------------------------------------------------
// Pass 2: fused params + apply over contiguous slices.
// ---------------------------------------------------------------------------
__global__ __launch_bounds__(256)
void ogn_apply(const float* __restrict__ data,
               const int* __restrict__ bid,
               const float* __restrict__ S1,
               const float* __restrict__ S2,
               const int* __restrict__ cnt,
               const float* __restrict__ w,
               const float* __restrict__ bias,
               float* __restrict__ out,
               int N, int rows_per_block) {
    __shared__ float4 lA[NBATCH * NGRP];
    __shared__ float4 lB[NBATCH * NGRP];

    const int t = threadIdx.x;
    if (t < NBATCH * NGRP) {
        int b = t >> 4;        // batch
        int g = t & 15;        // group == float4 chunk (CPG == 4)
        int base = b * NCH + g * CPG;
        float s1g = 0.f, s2g = 0.f;
#pragma unroll
        for (int k = 0; k < CPG; ++k) {
            s1g += S1[base + k];
            s2g += S2[base + k];
        }
        float countf    = (float)cnt[b] * (float)CPG;
        float inv_count = 1.f / (countf + EPSV);
        float mean      = s1g * inv_count;
        float var       = inv_count * (s2g - 2.f * mean * s1g + countf * mean * mean);
        float inv_std   = rsqrtf(var + EPSV);

        float4 wv = ((const float4*)w)[g];
        float4 bv = ((const float4*)bias)[g];
        float4 a4, b4;
        a4.x = inv_std * wv.x; b4.x = bv.x - mean * a4.x;
        a4.y = inv_std * wv.y; b4.y = bv.y - mean * a4.y;
        a4.z = inv_std * wv.z; b4.z = bv.z - mean * a4.z;
        a4.w = inv_std * wv.w; b4.w = bv.w - mean * a4.w;
        lA[b * NGRP + g] = a4;
        lB[b * NGRP + g] = b4;
    }
    __syncthreads();

    const int c4    = t & 15;
    const int rlane = t >> 4;

    long long row_begin = (long long)blockIdx.x * rows_per_block;
    long long row_end   = row_begin + rows_per_block;
    if (row_begin > N) row_begin = N;
    if (row_end > N) row_end = N;
    if (row_begin >= row_end) return;

    const float4* d4 = (const float4*)data;
    float4* o4 = (float4*)out;

    const int b0 = bid[row_begin];
    const int b1 = bid[row_end - 1];

#define FMA4(res_, vv, a_, b_) do {                                    \
        (res_).x = fmaf((vv).x, (a_).x, (b_).x);                       \
        (res_).y = fmaf((vv).y, (a_).y, (b_).y);                       \
        (res_).z = fmaf((vv).z, (a_).z, (b_).z);                       \
        (res_).w = fmaf((vv).w, (a_).w, (b_).w);                       \
    } while (0)

    if (b0 == b1) {
        // ---------- fast path: A/B hoisted to registers, pure stream ----------
        const float4 a  = lA[b0 * NGRP + c4];
        const float4 bb = lB[b0 * NGRP + c4];
        long long r = row_begin + rlane;
        for (; r + 48 < row_end; r += 64) {
            float4 v0 = d4[r * 16 + c4];
            float4 v1 = d4[(r + 16) * 16 + c4];
            float4 v2 = d4[(r + 32) * 16 + c4];
            float4 v3 = d4[(r + 48) * 16 + c4];
            f32x4 r0, r1, r2, r3;
            FMA4(r0, v0, a, bb);
            FMA4(r1, v1, a, bb);
            FMA4(r2, v2, a, bb);
            FMA4(r3, v3, a, bb);
            __builtin_nontemporal_store(r0, (f32x4*)&o4[r * 16 + c4]);
            __builtin_nontemporal_store(r1, (f32x4*)&o4[(r + 16) * 16 + c4]);
            __builtin_nontemporal_store(r2, (f32x4*)&o4[(r + 32) * 16 + c4]);
            __builtin_nontemporal_store(r3, (f32x4*)&o4[(r + 48) * 16 + c4]);
        }
        for (; r < row_end; r += 16) {
            float4 v = d4[r * 16 + c4];
            f32x4 res;
            FMA4(res, v, a, bb);
            __builtin_nontemporal_store(res, (f32x4*)&o4[r * 16 + c4]);
        }
    } else {
        // ---------- slow path: per-row bid -> LDS lookup ----------
        for (long long r = row_begin + rlane; r < row_end; r += 16) {
            int b = bid[r];
            float4 v  = d4[r * 16 + c4];
            float4 a  = lA[b * NGRP + c4];
            float4 bb = lB[b * NGRP + c4];
            f32x4 res;
            FMA4(res, v, a, bb);
            __builtin_nontemporal_store(res, (f32x4*)&o4[r * 16 + c4]);
        }
    }
#undef FMA4
}

extern "C" void kernel_launch(void* const* d_in, const int* in_sizes, int n_in,
                              void* d_out, int out_size, void* d_ws, size_t ws_size,
                              hipStream_t stream) {
    const float* data = (const float*)d_in[0];
    const int*   bid  = (const int*)d_in[1];
    const float* w    = (const float*)d_in[2];
    const float* bias = (const float*)d_in[3];
    float* out = (float*)d_out;

    int N = in_sizes[1];  // batch_id count

    char* ws = (char*)d_ws;
    float* S1  = (float*)(ws + 0);
    float* S2  = (float*)(ws + 4096);
    int*   cnt = (int*)  (ws + 8192);

    // zero the accumulator region (S1, S2, cnt)
    hipMemsetAsync(d_ws, 0, 8256, stream);

    const int NB = 2048;  // fully-resident sweep: leaves data L3-resident
    int rows_per_block = (int)(((long long)N + NB - 1) / NB);

    ogn_stats<<<NB, 256, 0, stream>>>(data, bid, S1, S2, cnt, N, rows_per_block);
    ogn_apply<<<NB, 256, 0, stream>>>(data, bid, S1, S2, cnt, w, bias, out,
                                      N, rows_per_block);
}